// Round 7
// baseline (249.429 us; speedup 1.0000x reference)
//
#include <hip/hip_runtime.h>
#include <hip/hip_bf16.h>

#define E_TOT 50000
#define EP    50176            // padded e-stride for NLQT (multiple of 512)
#define NF    64
#define B_TOT 64
#define B_TILE 8
#define BLOCK  256
#define LOG2E 1.4426950408889634f

// out[b,e] = sum_f exp(-(HL[b,f] - NL[e,f] - c[f])^2 / var[f]) * W[b,f]
// q[f]=sqrt(log2e/var[f]); A[b,f]=(HL-c)*q; n[e,f]=NL*q; phi=exp2(-(A-n)^2)
//
// R7: pre-transpose NLQT[f][e] = NL[e][f]*q[f] into ws so the main kernel's
// n-loads are coalesced float2 (kills the 64-line-per-instr splatter that
// scaled with 64/B_TILE passes). E_PT=2 halves LDS broadcast traffic.
// Floor: VALU+trans issue ~14cyc per 64-elem wave group ~= 18us/SIMD.

// ---- transpose + scale: NLQT[f][e] = NL[e][f] * q[f], 64x64 LDS tiles ----
__global__ void transpose_kernel(const float* __restrict__ NL,
                                 const float* __restrict__ varr,
                                 float* __restrict__ nlqt)
{
    __shared__ float tile[NF][NF + 1];
    __shared__ float qs[NF];
    const int tid = threadIdx.x;
    const int e0  = blockIdx.x * 64;

    if (tid < NF) qs[tid] = sqrtf(LOG2E / varr[tid]);

#pragma unroll
    for (int rep = 0; rep < 16; ++rep) {
        const int l  = rep * 256 + tid;
        const int el = l >> 6, f = l & (NF - 1);
        int e = e0 + el; if (e > E_TOT - 1) e = E_TOT - 1;   // clamp tail reads
        tile[f][el] = NL[(size_t)e * NF + f];                // coalesced read
    }
    __syncthreads();
#pragma unroll
    for (int rep = 0; rep < 16; ++rep) {
        const int l  = rep * 256 + tid;
        const int f  = l >> 6, el = l & (NF - 1);
        nlqt[(size_t)f * EP + e0 + el] = tile[f][el] * qs[f]; // coalesced write
    }
}

// ---- main: thread owns 2 consecutive e's, 8 b's staged in LDS ----
__global__ __launch_bounds__(BLOCK, 4)
void kbln_main(const float* __restrict__ NL,
               const float* __restrict__ c,
               const float* __restrict__ varr,
               const float* __restrict__ NFW,
               const int*   __restrict__ head_ids,
               const int*   __restrict__ rel_ids,
               const float* __restrict__ nlqt,   // [NF][EP]
               float*       __restrict__ out)    // [B, E]
{
    __shared__ float sQ[NF];
    __shared__ float4 sA[B_TILE][NF / 4];
    __shared__ float4 sW[B_TILE][NF / 4];

    const int tid = threadIdx.x;
    const int b0  = blockIdx.y * B_TILE;

    if (tid < NF) sQ[tid] = sqrtf(LOG2E / varr[tid]);
    __syncthreads();

    for (int s = tid; s < B_TILE * NF; s += BLOCK) {
        const int bi = s >> 6;
        const int f  = s & (NF - 1);
        const int h  = head_ids[b0 + bi];
        const int r  = rel_ids[b0 + bi];
        reinterpret_cast<float*>(&sA[bi][0])[f] =
            (NL[(size_t)h * NF + f] - c[f]) * sQ[f];
        reinterpret_cast<float*>(&sW[bi][0])[f] = NFW[(size_t)r * NF + f];
    }
    __syncthreads();

    const int e0 = blockIdx.x * (BLOCK * 2) + 2 * tid;   // even; < EP always
    const float* base = nlqt + e0;

    float2 acc[B_TILE];
#pragma unroll
    for (int bi = 0; bi < B_TILE; ++bi) { acc[bi].x = 0.f; acc[bi].y = 0.f; }

#pragma unroll
    for (int i = 0; i < NF / 4; ++i) {
        // 4 coalesced float2 loads: n for f = 4i..4i+3, e = e0, e0+1
        const float2 n0 = *reinterpret_cast<const float2*>(base + (size_t)(4 * i + 0) * EP);
        const float2 n1 = *reinterpret_cast<const float2*>(base + (size_t)(4 * i + 1) * EP);
        const float2 n2 = *reinterpret_cast<const float2*>(base + (size_t)(4 * i + 2) * EP);
        const float2 n3 = *reinterpret_cast<const float2*>(base + (size_t)(4 * i + 3) * EP);
#pragma unroll
        for (int bi = 0; bi < B_TILE; ++bi) {
            const float4 a = sA[bi][i];   // broadcast ds_read_b128
            const float4 w = sW[bi][i];
            float t;
            t = a.x - n0.x; acc[bi].x = fmaf(__builtin_amdgcn_exp2f(-(t * t)), w.x, acc[bi].x);
            t = a.x - n0.y; acc[bi].y = fmaf(__builtin_amdgcn_exp2f(-(t * t)), w.x, acc[bi].y);
            t = a.y - n1.x; acc[bi].x = fmaf(__builtin_amdgcn_exp2f(-(t * t)), w.y, acc[bi].x);
            t = a.y - n1.y; acc[bi].y = fmaf(__builtin_amdgcn_exp2f(-(t * t)), w.y, acc[bi].y);
            t = a.z - n2.x; acc[bi].x = fmaf(__builtin_amdgcn_exp2f(-(t * t)), w.z, acc[bi].x);
            t = a.z - n2.y; acc[bi].y = fmaf(__builtin_amdgcn_exp2f(-(t * t)), w.z, acc[bi].y);
            t = a.w - n3.x; acc[bi].x = fmaf(__builtin_amdgcn_exp2f(-(t * t)), w.w, acc[bi].x);
            t = a.w - n3.y; acc[bi].y = fmaf(__builtin_amdgcn_exp2f(-(t * t)), w.w, acc[bi].y);
        }
    }

    if (e0 + 1 < E_TOT) {   // E_TOT even -> pairs never split
#pragma unroll
        for (int bi = 0; bi < B_TILE; ++bi) {
            *reinterpret_cast<float2*>(&out[(size_t)(b0 + bi) * E_TOT + e0]) = acc[bi];
        }
    }
}

// ---- fallback (R2 structure) if ws is too small for NLQT ----
__global__ __launch_bounds__(BLOCK, 8)
void kbln_fallback(const float* __restrict__ NL, const float* __restrict__ c,
                   const float* __restrict__ varr, const float* __restrict__ NFW,
                   const int* __restrict__ head_ids, const int* __restrict__ rel_ids,
                   float* __restrict__ out)
{
    __shared__ float sQ[NF];
    __shared__ float4 sA[B_TILE][NF / 4];
    __shared__ float4 sW[B_TILE][NF / 4];
    const int tid = threadIdx.x;
    const int b0  = blockIdx.y * B_TILE;
    const int e   = blockIdx.x * BLOCK + tid;
    if (tid < NF) sQ[tid] = sqrtf(LOG2E / varr[tid]);
    __syncthreads();
    for (int s = tid; s < B_TILE * NF; s += BLOCK) {
        const int bi = s >> 6, f = s & (NF - 1);
        const int h = head_ids[b0 + bi], r = rel_ids[b0 + bi];
        reinterpret_cast<float*>(&sA[bi][0])[f] = (NL[(size_t)h * NF + f] - c[f]) * sQ[f];
        reinterpret_cast<float*>(&sW[bi][0])[f] = NFW[(size_t)r * NF + f];
    }
    __syncthreads();
    if (e >= E_TOT) return;
    const float4* nl4 = reinterpret_cast<const float4*>(NL + (size_t)e * NF);
    const float4* q4  = reinterpret_cast<const float4*>(sQ);
    float acc[B_TILE];
#pragma unroll
    for (int bi = 0; bi < B_TILE; ++bi) acc[bi] = 0.0f;
#pragma unroll
    for (int i = 0; i < NF / 4; ++i) {
        const float4 v = nl4[i];
        const float4 q = q4[i];
        float4 n; n.x = v.x * q.x; n.y = v.y * q.y; n.z = v.z * q.z; n.w = v.w * q.w;
#pragma unroll
        for (int bi = 0; bi < B_TILE; ++bi) {
            const float4 a = sA[bi][i];
            const float4 w = sW[bi][i];
            float t;
            t = a.x - n.x; acc[bi] = fmaf(__builtin_amdgcn_exp2f(-(t * t)), w.x, acc[bi]);
            t = a.y - n.y; acc[bi] = fmaf(__builtin_amdgcn_exp2f(-(t * t)), w.y, acc[bi]);
            t = a.z - n.z; acc[bi] = fmaf(__builtin_amdgcn_exp2f(-(t * t)), w.z, acc[bi]);
            t = a.w - n.w; acc[bi] = fmaf(__builtin_amdgcn_exp2f(-(t * t)), w.w, acc[bi]);
        }
    }
#pragma unroll
    for (int bi = 0; bi < B_TILE; ++bi) out[(size_t)(b0 + bi) * E_TOT + e] = acc[bi];
}

extern "C" void kernel_launch(void* const* d_in, const int* in_sizes, int n_in,
                              void* d_out, int out_size, void* d_ws, size_t ws_size,
                              hipStream_t stream)
{
    const float* NL       = (const float*)d_in[0];
    const float* c        = (const float*)d_in[1];
    const float* varr     = (const float*)d_in[2];
    const float* NFW      = (const float*)d_in[3];
    const int*   head_ids = (const int*)d_in[4];
    const int*   rel_ids  = (const int*)d_in[5];
    float*       out      = (float*)d_out;

    const size_t nlqt_bytes = (size_t)NF * EP * sizeof(float);
    if (ws_size >= nlqt_bytes) {
        float* nlqt = (float*)d_ws;
        transpose_kernel<<<dim3((EP + 63) / 64), dim3(256), 0, stream>>>(NL, varr, nlqt);
        dim3 grid((E_TOT + BLOCK * 2 - 1) / (BLOCK * 2), B_TOT / B_TILE);
        kbln_main<<<grid, dim3(BLOCK), 0, stream>>>(NL, c, varr, NFW,
                                                    head_ids, rel_ids, nlqt, out);
    } else {
        dim3 grid((E_TOT + BLOCK - 1) / BLOCK, B_TOT / B_TILE);
        kbln_fallback<<<grid, dim3(BLOCK), 0, stream>>>(NL, c, varr, NFW,
                                                        head_ids, rel_ids, out);
    }
}